// Round 3
// baseline (189.403 us; speedup 1.0000x reference)
//
#include <hip/hip_runtime.h>

#define KDIM 4096
#define NDIM 4096
#define BM 256
#define BN 256
#define BK 128            // K bytes (int8) per tile
#define NTILE (KDIM / BK) // 32

using i32x4 = __attribute__((ext_vector_type(4))) int;

__device__ __forceinline__ void g2l16(const void* g, void* l) {
  __builtin_amdgcn_global_load_lds(
      (const __attribute__((address_space(1))) void*)g,
      (__attribute__((address_space(3))) void*)l,
      16, 0, 0);
}

// ---------------- detect: weight buffer int32-expanded (flag=1) or raw int8 (flag=0)?
__global__ void w8l_detect(const int* __restrict__ w32, int* __restrict__ flag) {
  __shared__ int s;
  const int t = threadIdx.x;
  if (t == 0) s = 1;
  __syncthreads();
  bool oob = false;
#pragma unroll
  for (int i = 0; i < 16; ++i) {
    int v = w32[t * 16 + i];
    if (v < -128 || v > 127) oob = true;
  }
  if (oob) atomicAnd(&s, 0);
  __syncthreads();
  if (t == 0) *flag = s;
}

// ---------------- pack int32 weights to int8 (only runs when flag==1)
__global__ void w8l_pack(const void* __restrict__ wsrc, const int* __restrict__ flag,
                         signed char* __restrict__ wq) {
  if (*flag == 0) return;  // GEMM reads the original int8 buffer directly
  const int t = blockIdx.x * blockDim.x + threadIdx.x;
  const int4* s = (const int4*)wsrc;
  int4 a = s[t * 4 + 0], b = s[t * 4 + 1], c = s[t * 4 + 2], d = s[t * 4 + 3];
  int4 o;
  o.x = (a.x & 255) | ((a.y & 255) << 8) | ((a.z & 255) << 16) | ((a.w & 255) << 24);
  o.y = (b.x & 255) | ((b.y & 255) << 8) | ((b.z & 255) << 16) | ((b.w & 255) << 24);
  o.z = (c.x & 255) | ((c.y & 255) << 8) | ((c.z & 255) << 16) | ((c.w & 255) << 24);
  o.w = (d.x & 255) | ((d.y & 255) << 8) | ((d.z & 255) << 16) | ((d.w & 255) << 24);
  ((int4*)wq)[t] = o;
}

// ---------------- quantize activations: 16 floats / thread
__global__ void w8l_quant(const float* __restrict__ x, const float* __restrict__ xs,
                          signed char* __restrict__ xq) {
  const int t = blockIdx.x * blockDim.x + threadIdx.x;
  const float s = *xs;
  const float4* x4 = (const float4*)x;
  int4 o;
  int* op = (int*)&o;
#pragma unroll
  for (int q = 0; q < 4; ++q) {
    float4 f = x4[t * 4 + q];
    int v0 = __float2int_rn(f.x / s);
    int v1 = __float2int_rn(f.y / s);
    int v2 = __float2int_rn(f.z / s);
    int v3 = __float2int_rn(f.w / s);
    v0 = v0 < -128 ? -128 : (v0 > 127 ? 127 : v0);
    v1 = v1 < -128 ? -128 : (v1 > 127 ? 127 : v1);
    v2 = v2 < -128 ? -128 : (v2 > 127 ? 127 : v2);
    v3 = v3 < -128 ? -128 : (v3 > 127 ? 127 : v3);
    op[q] = (v0 & 255) | ((v1 & 255) << 8) | ((v2 & 255) << 16) | ((v3 & 255) << 24);
  }
  ((int4*)xq)[t] = o;
}

// ---------------- 256x256 i8 GEMM, 2 barriers/K-tile, in-wave LDS/MFMA overlap
// LDS per buffer b: A tile at b*65536, B at +32768. Row=128B=8 slots of 16B;
// LDS(r,slot) holds global k-chunk (slot ^ (r&7)) (inverse-swizzled source,
// linear dest, swizzled read — rule #21).
__global__ __launch_bounds__(512, 2) void w8l_gemm8(
    const signed char* __restrict__ Aq,
    const signed char* __restrict__ Wraw, const signed char* __restrict__ Wpk,
    const int* __restrict__ flag,
    const float* __restrict__ scale, const float* __restrict__ xscale,
    const float* __restrict__ bias, float* __restrict__ out, int nbn) {
  __shared__ signed char lds[131072];

  const signed char* __restrict__ Wq = (*flag) ? Wpk : Wraw;

  const int tid = threadIdx.x;
  const int lane = tid & 63;
  const int wid = tid >> 6;  // 0..7
  const int wr = wid >> 2;   // 0..1 (wave rows: 128)
  const int wc = wid & 3;    // 0..3 (wave cols: 64)
  const int l15 = lane & 15;
  const int l4 = lane >> 4;

  // XCD-aware bijective swizzle (grid = 512, divisible by 8)
  const int nwg = gridDim.x;
  const int cpx = nwg >> 3;
  const int bid = blockIdx.x;
  const int swz = (bid & 7) * cpx + (bid >> 3);
  const int bm = swz / nbn, bn = swz % nbn;
  const int m0 = bm * BM, n0 = bn * BN;

  // staging: one g2l16 issue moves 8 KB (64 rows x 128 B) across 512 threads
  const unsigned lin = (unsigned)tid * 16u;
  const unsigned r_in = lin >> 7;  // 0..63
  const unsigned c16 = (lin >> 4) & 7;
  const unsigned swcol = ((c16 ^ (r_in & 7)) << 4);
  const signed char* agp = Aq + (size_t)(m0 + r_in) * KDIM + swcol;
  const signed char* wgp = Wq + (size_t)(n0 + r_in) * KDIM + swcol;
  const unsigned ldsoff_thr = r_in * 128u + c16 * 16u;

#define ISSUE_TILE(t)                                                     \
  do {                                                                    \
    const int t_ = (t);                                                   \
    const size_t koff_ = (size_t)t_ * BK;                                 \
    signed char* lb_ = lds + (unsigned)(t_ & 1) * 65536u + ldsoff_thr;    \
    _Pragma("unroll") for (int u = 0; u < 4; ++u)                         \
      g2l16(agp + (size_t)(u * 64) * KDIM + koff_, lb_ + u * 8192);       \
    _Pragma("unroll") for (int u = 0; u < 4; ++u)                         \
      g2l16(wgp + (size_t)(u * 64) * KDIM + koff_, lb_ + 32768 + u * 8192); \
  } while (0)

#define LDFRAG(base, row, sl) \
  (*(const i32x4*)((base) + (row) * 128 + (((((sl) * 4) + l4) ^ ((row) & 7)) * 16)))

  i32x4 acc[8][4] = {};

  ISSUE_TILE(0);

#pragma unroll 1
  for (int kt = 0; kt < NTILE; ++kt) {
    // prefetch tile kt+1 (other buffer; prev-tile reads done per end-barrier)
    if (kt + 1 < NTILE) {
      ISSUE_TILE(kt + 1);
      asm volatile("s_waitcnt vmcnt(8)" ::: "memory");  // tile kt fully landed
    } else {
      asm volatile("s_waitcnt vmcnt(0)" ::: "memory");
    }
    __builtin_amdgcn_s_barrier();          // all waves' kt loads landed
    __builtin_amdgcn_sched_barrier(0);

    const signed char* Ab = &lds[(kt & 1) * 65536];
    const signed char* Bb = Ab + 32768;
    i32x4 a0[4][2], a1[4][2], b01[2][2], b23[2][2];

    // seg A: a0 + b01 (12 reads), must land before Q00
#pragma unroll
    for (int i = 0; i < 4; ++i)
#pragma unroll
      for (int s = 0; s < 2; ++s) a0[i][s] = LDFRAG(Ab, wr * 128 + i * 16 + l15, s);
#pragma unroll
    for (int j = 0; j < 2; ++j)
#pragma unroll
      for (int s = 0; s < 2; ++s) b01[j][s] = LDFRAG(Bb, wc * 64 + j * 16 + l15, s);
    asm volatile("s_waitcnt lgkmcnt(0)" ::: "memory");
    __builtin_amdgcn_sched_barrier(0);

    // issue b23 (4 reads) then a1 (8 reads) — serviced under Q00/Q01 MFMA
#pragma unroll
    for (int j = 0; j < 2; ++j)
#pragma unroll
      for (int s = 0; s < 2; ++s) b23[j][s] = LDFRAG(Bb, wc * 64 + (j + 2) * 16 + l15, s);
    __builtin_amdgcn_sched_barrier(0);  // pin issue order: b23 before a1 (lgkm counts)
#pragma unroll
    for (int i = 0; i < 4; ++i)
#pragma unroll
      for (int s = 0; s < 2; ++s) a1[i][s] = LDFRAG(Ab, wr * 128 + (i + 4) * 16 + l15, s);
    __builtin_amdgcn_sched_barrier(0);  // all issues precede MFMA cluster

    __builtin_amdgcn_s_setprio(1);      // Q00: a0 x b01
#pragma unroll
    for (int i = 0; i < 4; ++i)
#pragma unroll
      for (int j = 0; j < 2; ++j)
#pragma unroll
        for (int s = 0; s < 2; ++s)
          acc[i][j] = __builtin_amdgcn_mfma_i32_16x16x64_i8(a0[i][s], b01[j][s], acc[i][j], 0, 0, 0);
    __builtin_amdgcn_s_setprio(0);

    asm volatile("s_waitcnt lgkmcnt(8)" ::: "memory");  // b23 landed (a1 in flight)
    __builtin_amdgcn_sched_barrier(0);
    __builtin_amdgcn_s_setprio(1);      // Q01: a0 x b23
#pragma unroll
    for (int i = 0; i < 4; ++i)
#pragma unroll
      for (int j = 0; j < 2; ++j)
#pragma unroll
        for (int s = 0; s < 2; ++s)
          acc[i][j + 2] = __builtin_amdgcn_mfma_i32_16x16x64_i8(a0[i][s], b23[j][s], acc[i][j + 2], 0, 0, 0);
    __builtin_amdgcn_s_setprio(0);

    asm volatile("s_waitcnt lgkmcnt(0)" ::: "memory");  // a1 landed
    __builtin_amdgcn_sched_barrier(0);
    __builtin_amdgcn_s_setprio(1);      // Q11: a1 x b23 ; Q10: a1 x b01
#pragma unroll
    for (int i = 0; i < 4; ++i)
#pragma unroll
      for (int j = 0; j < 2; ++j)
#pragma unroll
        for (int s = 0; s < 2; ++s)
          acc[i + 4][j + 2] = __builtin_amdgcn_mfma_i32_16x16x64_i8(a1[i][s], b23[j][s], acc[i + 4][j + 2], 0, 0, 0);
#pragma unroll
    for (int i = 0; i < 4; ++i)
#pragma unroll
      for (int j = 0; j < 2; ++j)
#pragma unroll
        for (int s = 0; s < 2; ++s)
          acc[i + 4][j] = __builtin_amdgcn_mfma_i32_16x16x64_i8(a1[i][s], b01[j][s], acc[i + 4][j], 0, 0, 0);
    __builtin_amdgcn_s_setprio(0);
    __builtin_amdgcn_sched_barrier(0);
    __builtin_amdgcn_s_barrier();       // all waves done reading tile kt
  }

  // epilogue: C/D layout col=lane&15, row=(lane>>4)*4+reg [m89, dtype-indep]
  const float cs = scale[0] * xscale[0];
#pragma unroll
  for (int j = 0; j < 4; ++j) {
    const int n = n0 + wc * 64 + j * 16 + l15;
    const float bj = bias[n];
#pragma unroll
    for (int i = 0; i < 8; ++i) {
      const int m = m0 + wr * 128 + i * 16 + l4 * 4;
      float* o = out + (size_t)m * NDIM + n;
#pragma unroll
      for (int v = 0; v < 4; ++v)
        o[(size_t)v * NDIM] = (float)acc[i][j][v] * cs + bj;
    }
  }
#undef ISSUE_TILE
#undef LDFRAG
}

extern "C" void kernel_launch(void* const* d_in, const int* in_sizes, int n_in,
                              void* d_out, int out_size, void* d_ws, size_t ws_size,
                              hipStream_t stream) {
  const float* x = (const float*)d_in[0];
  const void* w = d_in[1];
  const float* scale = (const float*)d_in[2];
  const float* xscale = (const float*)d_in[3];
  const float* bias = (const float*)d_in[4];
  float* out = (float*)d_out;

  const int M = in_sizes[0] / KDIM;  // 8192

  int* flag = (int*)d_ws;
  signed char* wq = (signed char*)d_ws + 256;
  signed char* aq = wq + (size_t)NDIM * KDIM;

  const size_t need = 256 + (size_t)NDIM * KDIM + (size_t)M * KDIM;
  if (ws_size < need) return;

  w8l_detect<<<1, 256, 0, stream>>>((const int*)w, flag);
  w8l_pack<<<(NDIM * KDIM / 16) / 256, 256, 0, stream>>>(w, flag, wq);
  w8l_quant<<<(M * KDIM / 16) / 256, 256, 0, stream>>>(x, xscale, aq);

  const int nbn = NDIM / BN;  // 16
  w8l_gemm8<<<(M / BM) * nbn, 512, 0, stream>>>(
      aq, (const signed char*)w, wq, flag, scale, xscale, bias, out, nbn);
}

// Round 4
// 181.548 us; speedup vs baseline: 1.0433x; 1.0433x over previous
//
#include <hip/hip_runtime.h>

#define KDIM 4096
#define NDIM 4096
#define BM 256
#define BN 256
#define BK 128            // K bytes (int8) per tile
#define NTILE (KDIM / BK) // 32

using i32x4 = __attribute__((ext_vector_type(4))) int;

__device__ __forceinline__ void g2l16(const void* g, void* l) {
  __builtin_amdgcn_global_load_lds(
      (const __attribute__((address_space(1))) void*)g,
      (__attribute__((address_space(3))) void*)l,
      16, 0, 0);
}

// ---------------- detect: weight buffer int32-expanded (flag=1) or raw int8 (flag=0)?
__global__ void w8l_detect(const int* __restrict__ w32, int* __restrict__ flag) {
  __shared__ int s;
  const int t = threadIdx.x;
  if (t == 0) s = 1;
  __syncthreads();
  bool oob = false;
#pragma unroll
  for (int i = 0; i < 16; ++i) {
    int v = w32[t * 16 + i];
    if (v < -128 || v > 127) oob = true;
  }
  if (oob) atomicAnd(&s, 0);
  __syncthreads();
  if (t == 0) *flag = s;
}

// ---------------- pack int32 weights to int8 (no-op when flag==0)
__global__ void w8l_pack(const void* __restrict__ wsrc, const int* __restrict__ flag,
                         signed char* __restrict__ wq) {
  if (*flag == 0) return;
  const int t = blockIdx.x * blockDim.x + threadIdx.x;
  const int4* s = (const int4*)wsrc;
  int4 a = s[t * 4 + 0], b = s[t * 4 + 1], c = s[t * 4 + 2], d = s[t * 4 + 3];
  int4 o;
  o.x = (a.x & 255) | ((a.y & 255) << 8) | ((a.z & 255) << 16) | ((a.w & 255) << 24);
  o.y = (b.x & 255) | ((b.y & 255) << 8) | ((b.z & 255) << 16) | ((b.w & 255) << 24);
  o.z = (c.x & 255) | ((c.y & 255) << 8) | ((c.z & 255) << 16) | ((c.w & 255) << 24);
  o.w = (d.x & 255) | ((d.y & 255) << 8) | ((d.z & 255) << 16) | ((d.w & 255) << 24);
  ((int4*)wq)[t] = o;
}

// ---------------- quantize activations: 16 floats / thread
__global__ void w8l_quant(const float* __restrict__ x, const float* __restrict__ xs,
                          signed char* __restrict__ xq) {
  const int t = blockIdx.x * blockDim.x + threadIdx.x;
  const float s = *xs;
  const float4* x4 = (const float4*)x;
  int4 o;
  int* op = (int*)&o;
#pragma unroll
  for (int q = 0; q < 4; ++q) {
    float4 f = x4[t * 4 + q];
    int v0 = __float2int_rn(f.x / s);
    int v1 = __float2int_rn(f.y / s);
    int v2 = __float2int_rn(f.z / s);
    int v3 = __float2int_rn(f.w / s);
    v0 = v0 < -128 ? -128 : (v0 > 127 ? 127 : v0);
    v1 = v1 < -128 ? -128 : (v1 > 127 ? 127 : v1);
    v2 = v2 < -128 ? -128 : (v2 > 127 ? 127 : v2);
    v3 = v3 < -128 ? -128 : (v3 > 127 ? 127 : v3);
    op[q] = (v0 & 255) | ((v1 & 255) << 8) | ((v2 & 255) << 16) | ((v3 & 255) << 24);
  }
  ((int4*)xq)[t] = o;
}

// ---------------- 256x256 i8 GEMM, register-fragment double-buffered pipeline.
// Reads for K-step s+1 are issued BEFORE the MFMA cluster for step s, so the
// compiler's auto lgkmcnt before each cluster waits only on already-serviced
// loads. One barrier + one vmcnt(0) + one lgkmcnt(0) per K-tile.
// LDS buffer b: A at b*65536, B at +32768; row = 128 B = 8 slots of 16 B;
// LDS(r,slot) holds global k-chunk (slot ^ (r&7)) (rule #21 construction).
__global__ __launch_bounds__(512, 2) void w8l_gemmp(
    const signed char* __restrict__ Aq,
    const signed char* __restrict__ Wraw, const signed char* __restrict__ Wpk,
    const int* __restrict__ flag,
    const float* __restrict__ scale, const float* __restrict__ xscale,
    const float* __restrict__ bias, float* __restrict__ out, int nbn) {
  __shared__ signed char lds[131072];

  const signed char* __restrict__ Wq = (*flag) ? Wpk : Wraw;

  const int tid = threadIdx.x;
  const int lane = tid & 63;
  const int wid = tid >> 6;  // 0..7
  const int wr = wid >> 2;   // 0..1 (wave tile: 128 rows)
  const int wc = wid & 3;    // 0..3 (wave tile: 64 cols)
  const int l15 = lane & 15;
  const int l4 = lane >> 4;

  // XCD-aware bijective swizzle (grid = 512, divisible by 8)
  const int nwg = gridDim.x;
  const int cpx = nwg >> 3;
  const int bid = blockIdx.x;
  const int swz = (bid & 7) * cpx + (bid >> 3);
  const int bm = swz / nbn, bn = swz % nbn;
  const int m0 = bm * BM, n0 = bn * BN;

  // staging: one g2l16 issue moves 8 KB (64 rows x 128 B) across 512 threads
  const unsigned lin = (unsigned)tid * 16u;
  const unsigned r_in = lin >> 7;  // 0..63
  const unsigned c16 = (lin >> 4) & 7;
  const unsigned swcol = ((c16 ^ (r_in & 7)) << 4);
  const signed char* agp = Aq + (size_t)(m0 + r_in) * KDIM + swcol;
  const signed char* wgp = Wq + (size_t)(n0 + r_in) * KDIM + swcol;
  const unsigned ldsoff_thr = r_in * 128u + c16 * 16u;

#define ISSUE_TILE(t)                                                       \
  do {                                                                      \
    const int t_ = (t);                                                     \
    const size_t koff_ = (size_t)t_ * BK;                                   \
    signed char* lb_ = lds + (unsigned)(t_ & 1) * 65536u + ldsoff_thr;      \
    _Pragma("unroll") for (int u = 0; u < 4; ++u)                           \
      g2l16(agp + (size_t)(u * 64) * KDIM + koff_, lb_ + u * 8192);         \
    _Pragma("unroll") for (int u = 0; u < 4; ++u)                           \
      g2l16(wgp + (size_t)(u * 64) * KDIM + koff_, lb_ + 32768 + u * 8192); \
  } while (0)

#define LDFRAG(base, row, sl) \
  (*(const i32x4*)((base) + (row) * 128 + (((((sl) * 4) + l4) ^ ((row) & 7)) * 16)))

#define READ_A(dst, base, sl)                                          \
  _Pragma("unroll") for (int i = 0; i < 8; ++i)                        \
      dst[i] = LDFRAG((base), wr * 128 + i * 16 + l15, (sl));
#define READ_B(dst, base, sl)                                          \
  _Pragma("unroll") for (int j = 0; j < 4; ++j)                        \
      dst[j] = LDFRAG((base), wc * 64 + j * 16 + l15, (sl));
#define MFMA_CLUSTER(av, bv)                                           \
  __builtin_amdgcn_s_setprio(1);                                       \
  _Pragma("unroll") for (int i = 0; i < 8; ++i)                        \
      _Pragma("unroll") for (int j = 0; j < 4; ++j)                    \
          acc[i][j] = __builtin_amdgcn_mfma_i32_16x16x64_i8(           \
              av[i], bv[j], acc[i][j], 0, 0, 0);                       \
  __builtin_amdgcn_s_setprio(0);

  i32x4 acc[8][4] = {};
  i32x4 aE[8], bE[4], aO[8], bO[4];

  // prologue: 2 tiles in flight; wait tile0 only
  ISSUE_TILE(0);
  ISSUE_TILE(1);
  asm volatile("s_waitcnt vmcnt(8)" ::: "memory");
  __builtin_amdgcn_s_barrier();
  __builtin_amdgcn_sched_barrier(0);
  READ_A(aE, lds, 0);
  READ_B(bE, lds + 32768, 0);
  __builtin_amdgcn_sched_barrier(0);

#pragma unroll 1
  for (int kt = 0; kt < NTILE; ++kt) {
    const signed char* Ab = &lds[(kt & 1) * 65536];
    const signed char* Bb = Ab + 32768;

    // ---- step A: issue s1 reads (same buffer), MFMA s0 under them
    READ_A(aO, Ab, 1);
    READ_B(bO, Bb, 1);
    __builtin_amdgcn_sched_barrier(0);
    MFMA_CLUSTER(aE, bE);
    __builtin_amdgcn_sched_barrier(0);
    asm volatile("s_waitcnt lgkmcnt(0)" ::: "memory");  // all buf(kt) reads drained
    __builtin_amdgcn_sched_barrier(0);

    // ---- step B: switch buffers, issue next-tile s0 reads + tile kt+2 staging,
    //              MFMA s1 under them
    if (kt + 1 < NTILE) {
      asm volatile("s_waitcnt vmcnt(0)" ::: "memory");  // g2l(kt+1) landed
      __builtin_amdgcn_s_barrier();                     // all waves: reads drained + loads visible
      __builtin_amdgcn_sched_barrier(0);
      const signed char* An = &lds[((kt + 1) & 1) * 65536];
      const signed char* Bn = An + 32768;
      READ_A(aE, An, 0);
      READ_B(bE, Bn, 0);
      if (kt + 2 < NTILE) ISSUE_TILE(kt + 2);  // overwrites buf(kt): safe post-barrier
      __builtin_amdgcn_sched_barrier(0);
    }
    MFMA_CLUSTER(aO, bO);
    __builtin_amdgcn_sched_barrier(0);
  }

  // epilogue: C/D layout col=lane&15, row=(lane>>4)*4+reg [m89, dtype-indep]
  const float cs = scale[0] * xscale[0];
#pragma unroll
  for (int j = 0; j < 4; ++j) {
    const int n = n0 + wc * 64 + j * 16 + l15;
    const float bj = bias[n];
#pragma unroll
    for (int i = 0; i < 8; ++i) {
      const int m = m0 + wr * 128 + i * 16 + l4 * 4;
      float* o = out + (size_t)m * NDIM + n;
#pragma unroll
      for (int v = 0; v < 4; ++v)
        o[(size_t)v * NDIM] = (float)acc[i][j][v] * cs + bj;
    }
  }
#undef ISSUE_TILE
#undef LDFRAG
#undef READ_A
#undef READ_B
#undef MFMA_CLUSTER
}

extern "C" void kernel_launch(void* const* d_in, const int* in_sizes, int n_in,
                              void* d_out, int out_size, void* d_ws, size_t ws_size,
                              hipStream_t stream) {
  const float* x = (const float*)d_in[0];
  const void* w = d_in[1];
  const float* scale = (const float*)d_in[2];
  const float* xscale = (const float*)d_in[3];
  const float* bias = (const float*)d_in[4];
  float* out = (float*)d_out;

  const int M = in_sizes[0] / KDIM;  // 8192

  int* flag = (int*)d_ws;
  signed char* wq = (signed char*)d_ws + 256;
  signed char* aq = wq + (size_t)NDIM * KDIM;

  const size_t need = 256 + (size_t)NDIM * KDIM + (size_t)M * KDIM;
  if (ws_size < need) return;

  w8l_detect<<<1, 256, 0, stream>>>((const int*)w, flag);
  w8l_pack<<<(NDIM * KDIM / 16) / 256, 256, 0, stream>>>(w, flag, wq);
  w8l_quant<<<(M * KDIM / 16) / 256, 256, 0, stream>>>(x, xscale, aq);

  const int nbn = NDIM / BN;  // 16
  w8l_gemmp<<<(M / BM) * nbn, 512, 0, stream>>>(
      aq, (const signed char*)w, wq, flag, scale, xscale, bias, out, nbn);
}